// Round 11
// baseline (379.062 us; speedup 1.0000x reference)
//
#include <hip/hip_runtime.h>
#include <hip/hip_bf16.h>
#include <hip/hip_cooperative_groups.h>
#include <stdint.h>

namespace cg = cooperative_groups;

// Problem constants
#define B_   2
#define T_   2048
#define D_   1024
#define H_   16
#define HD_  64
#define MEM_ 512
#define KV_  (MEM_ + T_)   // 2560
#define NIT_ (KV_ / 64)    // 40 kv-tiles of 64
#define NIT2_ (NIT_ / 2)   // 20 per kv-half

using bf16 = __bf16;
typedef __bf16 bf16x8 __attribute__((ext_vector_type(8)));
typedef float  f32x4  __attribute__((ext_vector_type(4)));
typedef short  s16x4  __attribute__((ext_vector_type(4)));
typedef short  s16x8  __attribute__((ext_vector_type(8)));

__device__ __forceinline__ f32x4 mfma16(bf16x8 a, bf16x8 b, f32x4 c) {
  return __builtin_amdgcn_mfma_f32_16x16x32_bf16(a, b, c, 0, 0, 0);
}

// Async global->LDS, 16B per lane (dest = wave-uniform base + lane*16).
__device__ __forceinline__ void gll16(const void* g, void* l) {
  __builtin_amdgcn_global_load_lds(
      (const __attribute__((address_space(1))) unsigned int*)g,
      (__attribute__((address_space(3))) unsigned int*)l, 16, 0, 0);
}

__device__ __forceinline__ unsigned short bf16_bits(float f) {
  bf16 h = (bf16)f;
  return __builtin_bit_cast(unsigned short, h);
}

__device__ __forceinline__ ushort4 pack4(f32x4 v) {
  ushort4 p;
  p.x = bf16_bits(v[0]); p.y = bf16_bits(v[1]);
  p.z = bf16_bits(v[2]); p.w = bf16_bits(v[3]);
  return p;
}

__device__ __forceinline__ bf16x8 cvt8(f32x4 a, f32x4 b) {
  bf16x8 r;
  r[0] = (bf16)a[0]; r[1] = (bf16)a[1]; r[2] = (bf16)a[2]; r[3] = (bf16)a[3];
  r[4] = (bf16)b[0]; r[5] = (bf16)b[1]; r[6] = (bf16)b[2]; r[7] = (bf16)b[3];
  return r;
}

// V^T kv-column permutation within each 64-aligned tile (R9: conflicts -98.8%).
__device__ __forceinline__ int vperm4(int u) {   // u multiple of 4
  int g = u >> 4, c = (u >> 2) & 3;
  return (g >> 1) * 32 + c * 8 + (g & 1) * 4;
}

// ---------------------------------------------------------------------------
// prep body for one virtual 256-thread block `vb` (same dispatch as R9 prep).
// ---------------------------------------------------------------------------
__device__ __forceinline__ void prep_vb(
    int vb, int t, const float* __restrict__ x, const float* __restrict__ wq,
    const float* __restrict__ memory, const float* __restrict__ wout,
    bf16* __restrict__ xb, bf16* __restrict__ wqb,
    bf16* __restrict__ mem_k, bf16* __restrict__ mem_vt,
    bf16* __restrict__ wob) {
  if (vb < 3584) {
    const float* s = (vb < 2048) ? x : wq;
    bf16* d = (vb < 2048) ? xb : wqb;
    size_t i = ((size_t)(vb < 2048 ? vb : vb - 2048) * 256 + t) * 8;
    f32x4 a = *(const f32x4*)(s + i);
    f32x4 b = *(const f32x4*)(s + i + 4);
    *(bf16x8*)(d + i) = cvt8(a, b);
  } else if (vb < 3840) {
    int idx8 = ((vb - 3584) * 256 + t) * 8;   // [0, 512*1024)
    int m = idx8 >> 10, d0 = idx8 & 1023;
    int hh = d0 >> 6, hd0 = d0 & 63;
    f32x4 a = *(const f32x4*)(memory + idx8);
    f32x4 b = *(const f32x4*)(memory + idx8 + 4);
    *(bf16x8*)&mem_k[((size_t)hh * MEM_ + m) * HD_ + hd0] = cvt8(a, b);
  } else if (vb < 4096) {
    int idx = (vb - 3840) * 256 + t;          // [0, 65536)
    int d = idx & 1023;
    int m0 = (idx >> 10) * 8;                 // 0..511 step 8
    bf16x8 r;
#pragma unroll
    for (int j = 0; j < 8; j++)
      r[j] = (bf16)memory[(size_t)(m0 + j) * D_ + d];
    int u = m0 & 63;
    bf16* dst = &mem_vt[(size_t)d * MEM_ + (m0 - u) + vperm4(u)];
    s16x8 rb = __builtin_bit_cast(s16x8, r);
    *(s16x4*)dst = __builtin_shufflevector(rb, rb, 0, 1, 2, 3);
    *(s16x4*)(dst + 8) = __builtin_shufflevector(rb, rb, 4, 5, 6, 7);
  } else {
    size_t i = ((size_t)(vb - 4096) * 256 + t) * 8;
    f32x4 a = *(const f32x4*)(wout + i);
    f32x4 b = *(const f32x4*)(wout + i + 4);
    *(bf16x8*)(wob + i) = cvt8(a, b);
  }
}

// ---------------------------------------------------------------------------
// gemm team (256 threads): C[M,N] = A[M,K]*W[N,K]^T, 128 x NTILE tile, BK=64,
// 4 waves (2x2), gll16 staging, both-sides XOR chunk swizzle.  Exactly the
// R9 gemm_bt body, parameterized by team id / local tid / LDS slice.
// Contains exactly 2 * (K/64) __syncthreads() calls (mirror count: 32 @K=1024).
// ---------------------------------------------------------------------------
template <int EPI, bool APLANE, int NTILE>
__device__ __forceinline__ void gemm_team(
    int raw, int lt, char* AB, char* BB,
    const bf16* __restrict__ A, const bf16* __restrict__ W,
    const float* __restrict__ bias,
    bf16* __restrict__ q_ws, bf16* __restrict__ k_ws,
    bf16* __restrict__ vt_ws, float* __restrict__ Cout,
    int K, int gx, int nwg) {
  constexpr int NF = NTILE / 32;
  constexpr int NB = NTILE / 32;
  int lin = (raw & 7) * (nwg >> 3) + (raw >> 3);   // bijective XCD swizzle
  const int m0 = (lin / gx) * 128;
  const int n0 = (lin % gx) * NTILE;
  const int w = lt >> 6;
  const int lane = lt & 63;
  const int lx = lane & 15;
  const int quad = lane >> 4;
  const int amb = (w & 1) * 64;
  const int bnb = (w >> 1) * (NTILE / 2);
  const int srow = lt >> 3;
  const int cs = (lt & 7) ^ (srow & 7);

  f32x4 acc[4][NF];
#pragma unroll
  for (int i = 0; i < 4; i++)
#pragma unroll
    for (int j = 0; j < NF; j++) acc[i][j] = (f32x4){0.f, 0.f, 0.f, 0.f};

  for (int k0 = 0; k0 < K; k0 += 64) {
    const bf16* pa[4];
#pragma unroll
    for (int g = 0; g < 4; g++) {
      int r = srow + 32 * g;
      if constexpr (APLANE) {
        int hh = k0 >> 6, hd = cs * 8;
        int mA = m0 + r;
        pa[g] = A + ((size_t)((mA >> 11) * H_ + hh) * T_ + (mA & 2047)) * HD_ + hd;
      } else {
        pa[g] = A + (size_t)(m0 + r) * K + k0 + cs * 8;
      }
    }
    const bf16* pb[NB];
#pragma unroll
    for (int g = 0; g < NB; g++)
      pb[g] = W + (size_t)(n0 + srow + 32 * g) * K + k0 + cs * 8;

    __syncthreads();   // prev iteration's LDS reads done
#pragma unroll
    for (int g = 0; g < 4; g++) gll16(pa[g], AB + g * 4096 + lt * 16);
#pragma unroll
    for (int g = 0; g < NB; g++) gll16(pb[g], BB + g * 4096 + lt * 16);
    __syncthreads();   // drains vmcnt -> tiles valid

    bf16x8 bfr[NF][2];
    const int rk = (lx & 7) << 4;
#pragma unroll
    for (int nt = 0; nt < NF; nt++)
#pragma unroll
      for (int kh = 0; kh < 2; kh++)
        bfr[nt][kh] = *(const bf16x8*)(BB + (size_t)(bnb + nt * 16 + lx) * 128 +
                                       ((quad * 16 + kh * 64) ^ rk));
#pragma unroll
    for (int mt = 0; mt < 4; mt++) {
      const char* ar = AB + (size_t)(amb + mt * 16 + lx) * 128;
      bf16x8 af0 = *(const bf16x8*)(ar + ((quad * 16) ^ rk));
      bf16x8 af1 = *(const bf16x8*)(ar + ((quad * 16 + 64) ^ rk));
#pragma unroll
      for (int nt = 0; nt < NF; nt++) {
        acc[mt][nt] = mfma16(af0, bfr[nt][0], acc[mt][nt]);
        acc[mt][nt] = mfma16(af1, bfr[nt][1], acc[mt][nt]);
      }
    }
  }

  // Epilogue. C/D layout: row = quad*4+reg (m), col = lane&15 (n).
  if (EPI == 0) {
#pragma unroll
    for (int mt = 0; mt < 4; mt++) {
      int mbase = m0 + amb + mt * 16 + quad * 4;
      int b = mbase >> 11;        // T=2048
      int t = mbase & 2047;
#pragma unroll
      for (int nt = 0; nt < NF; nt++) {
        int col = n0 + bnb + nt * 16 + lx;     // [0,3072)
        int which = col >> 10;                 // 0=q 1=k 2=v
        int d = col & 1023;
        int hh = d >> 6, hdi = d & 63;
        int bh = b * H_ + hh;
        if (which == 0) {
#pragma unroll
          for (int r = 0; r < 4; r++)
            q_ws[((size_t)bh * T_ + t + r) * HD_ + hdi] = (bf16)acc[mt][nt][r];
        } else if (which == 1) {
#pragma unroll
          for (int r = 0; r < 4; r++)
            k_ws[((size_t)bh * T_ + t + r) * HD_ + hdi] = (bf16)acc[mt][nt][r];
        } else {
          int u = t & 63;
          *(ushort4*)&vt_ws[((size_t)bh * HD_ + hdi) * T_ + (t - u) +
                            vperm4(u)] = pack4(acc[mt][nt]);
        }
      }
    }
  } else {
#pragma unroll
    for (int nt = 0; nt < NF; nt++) {
      int col = n0 + bnb + nt * 16 + lx;
      float bias_f = bias[col];
#pragma unroll
      for (int mt = 0; mt < 4; mt++) {
        int mbase = m0 + amb + mt * 16 + quad * 4;
#pragma unroll
        for (int r = 0; r < 4; r++)
          Cout[(size_t)(mbase + r) * D_ + col] = acc[mt][nt][r] + bias_f;
      }
    }
  }
}

// ---------------------------------------------------------------------------
// Flash attention body (R9, proven 51 us): kv-split x2, 512 threads, b128 PV
// via vperm4, ones-MFMA row-sum, counted vmcnt, linear kv-half merge.
// smem: 64 KB (K 32KB | V 32KB).
// ---------------------------------------------------------------------------
__device__ __forceinline__ void attn_body(
    int bx, int tid, char* smem,
    bf16* __restrict__ q_ws, const bf16* __restrict__ k_ws,
    const bf16* __restrict__ vt_ws, const bf16* __restrict__ mem_k,
    const bf16* __restrict__ mem_vt) {
  char* KB = smem;
  char* VB = smem + 32768;
  const int wh = tid >> 8;             // kv-half
  const int t2 = tid & 255;
  const int w = t2 >> 6;               // wave within half
  const int lane = tid & 63;
  const int lx = lane & 15;
  const int quad = lane >> 4;
  const int bh = bx & 31;              // XCD-locality
  const int qt = bx >> 5;              // 16 q-tiles of 128
  const int q0 = qt * 128 + w * 32;
  const int h = bh & 15;

  const int srow1 = t2 >> 3;               // 0..31
  const int sc1 = (t2 & 7) ^ (srow1 & 7);  // pre-swizzled source chunk

  char* KBh = KB + wh * 16384;
  char* VBh = VB + wh * 16384;

  bf16* qbase = q_ws + ((size_t)bh * T_ + q0) * HD_;

  const bf16* kpl = k_ws + (size_t)bh * T_ * HD_;
  const bf16* vpl = vt_ws + (size_t)bh * HD_ * T_;
  const bf16* mkp = mem_k + (size_t)h * MEM_ * HD_;   // per-head plane
  const bf16* mvp = mem_vt + (size_t)h * HD_ * MEM_;

  auto stage = [&](int it2, int bi) {
    const int kv0 = (wh * NIT2_ + it2) * 64;
    const bf16 *kp1, *kp2, *vp1, *vp2;
    if (kv0 < MEM_) {
      kp1 = mkp + (size_t)(kv0 + srow1) * HD_ + sc1 * 8;
      kp2 = kp1 + (size_t)32 * HD_;
      vp1 = mvp + (size_t)srow1 * MEM_ + kv0 + sc1 * 8;
      vp2 = vp1 + (size_t)32 * MEM_;
    } else {
      const int t0 = kv0 - MEM_;
      kp1 = kpl + (size_t)(t0 + srow1) * HD_ + sc1 * 8;
      kp2 = kp1 + (size_t)32 * HD_;
      vp1 = vpl + (size_t)srow1 * T_ + t0 + sc1 * 8;
      vp2 = vp1 + (size_t)32 * T_;
    }
    char* kb = KBh + bi * 8192;
    char* vb = VBh + bi * 8192;
    gll16(kp1, kb + t2 * 16);
    gll16(kp2, kb + t2 * 16 + 4096);
    gll16(vp1, vb + t2 * 16);
    gll16(vp2, vb + t2 * 16 + 4096);
  };

  const float QSCALE = 0.125f * 1.44269504089f;
  bf16x8 qf[2][2];
#pragma unroll
  for (int qg = 0; qg < 2; qg++)
#pragma unroll
    for (int hf = 0; hf < 2; hf++) {
      bf16x8 v = *(const bf16x8*)(qbase + (size_t)(qg * 16 + lx) * HD_ +
                                  hf * 32 + quad * 8);
#pragma unroll
      for (int i = 0; i < 8; i++)
        v[i] = (bf16)((float)v[i] * QSCALE);
      qf[qg][hf] = v;
    }

  bf16x8 ones;
#pragma unroll
  for (int i = 0; i < 8; i++) ones[i] = (bf16)1.0f;

  f32x4 o[4][2];
#pragma unroll
  for (int mt = 0; mt < 4; mt++)
#pragma unroll
    for (int qg = 0; qg < 2; qg++) o[mt][qg] = (f32x4){0.f, 0.f, 0.f, 0.f};
  f32x4 osum[2] = {(f32x4){0.f, 0.f, 0.f, 0.f}, (f32x4){0.f, 0.f, 0.f, 0.f}};

  stage(0, 0);

  for (int it = 0; it < NIT2_; it++) {
    const int cur = it & 1;
    if (it + 1 < NIT2_) {
      stage(it + 1, cur ^ 1);
      asm volatile("s_waitcnt vmcnt(4)" ::: "memory");
    } else {
      asm volatile("s_waitcnt vmcnt(0)" ::: "memory");
    }
    __builtin_amdgcn_s_barrier();
    __builtin_amdgcn_sched_barrier(0);

    const char* KBc = KBh + cur * 8192;
    const char* VBc = VBh + cur * 8192;
    const int sw = (lx & 7) << 4;
    f32x4 s[4][2];
    __builtin_amdgcn_s_setprio(1);
#pragma unroll
    for (int g = 0; g < 4; g++) {
      const char* kb = KBc + (size_t)(g * 16 + lx) * 128;
      bf16x8 ka0 = *(const bf16x8*)(kb + ((quad * 16) ^ sw));
      bf16x8 ka1 = *(const bf16x8*)(kb + ((64 + quad * 16) ^ sw));
#pragma unroll
      for (int qg = 0; qg < 2; qg++) {
        s[g][qg] = (f32x4){0.f, 0.f, 0.f, 0.f};
        s[g][qg] = mfma16(ka0, qf[qg][0], s[g][qg]);
        s[g][qg] = mfma16(ka1, qf[qg][1], s[g][qg]);
      }
    }
    __builtin_amdgcn_s_setprio(0);

    s16x8 pk[2][2];
#pragma unroll
    for (int qg = 0; qg < 2; qg++) {
#pragma unroll
      for (int g = 0; g < 4; g++) {
#pragma unroll
        for (int r = 0; r < 4; r++) {
          float p = __builtin_amdgcn_exp2f(s[g][qg][r]);
          pk[qg][g >> 1][(g & 1) * 4 + r] = (short)bf16_bits(p);
        }
      }
    }

    __builtin_amdgcn_s_setprio(1);
#pragma unroll
    for (int mt = 0; mt < 4; mt++) {
      const char* vb = VBc + (size_t)(mt * 16 + lx) * 128;
#pragma unroll
      for (int p = 0; p < 2; p++) {
        bf16x8 va = *(const bf16x8*)(vb + ((p * 64 + quad * 16) ^ sw));
#pragma unroll
        for (int qg = 0; qg < 2; qg++)
          o[mt][qg] = mfma16(va, __builtin_bit_cast(bf16x8, pk[qg][p]),
                             o[mt][qg]);
      }
    }
#pragma unroll
    for (int p = 0; p < 2; p++)
#pragma unroll
      for (int qg = 0; qg < 2; qg++)
        osum[qg] = mfma16(ones, __builtin_bit_cast(bf16x8, pk[qg][p]),
                          osum[qg]);
    __builtin_amdgcn_s_setprio(0);

    __builtin_amdgcn_sched_barrier(0);
    __builtin_amdgcn_s_barrier();
  }

  float* OS = (float*)KB;
  float* OSS = (float*)VB;
  if (wh == 1) {
    float* dst = OS + t2 * 32;
#pragma unroll
    for (int mt = 0; mt < 4; mt++)
#pragma unroll
      for (int qg = 0; qg < 2; qg++) {
        int c = mt * 2 + qg;
        *(f32x4*)(dst + ((c ^ (t2 & 7)) * 4)) = o[mt][qg];
      }
    OSS[t2 * 2 + 0] = osum[0][0];
    OSS[t2 * 2 + 1] = osum[1][0];
  }
  __syncthreads();
  if (wh == 0) {
    const float* src = OS + t2 * 32;
    float inv[2] = {1.f / (osum[0][0] + OSS[t2 * 2 + 0]),
                    1.f / (osum[1][0] + OSS[t2 * 2 + 1])};
#pragma unroll
    for (int qg = 0; qg < 2; qg++) {
#pragma unroll
      for (int mt = 0; mt < 4; mt++) {
        int c = mt * 2 + qg;
        f32x4 po = *(const f32x4*)(src + ((c ^ (t2 & 7)) * 4));
        f32x4 ov;
#pragma unroll
        for (int r = 0; r < 4; r++) ov[r] = (o[mt][qg][r] + po[r]) * inv[qg];
        *(ushort4*)(qbase + (size_t)(qg * 16 + lx) * HD_ + mt * 16 + quad * 4)
            = pack4(ov);
      }
    }
  }
}

// ---------------------------------------------------------------------------
// FUSED cooperative kernel: prep -> gemm1 -> attn -> [wout conv] -> gemm2,
// grid 512 x 512 threads (2 blocks/CU), grid.sync() between phases.
// Removes 3-4 inter-kernel launch gaps (~25 us).  Each phase is an exact
// copy of the proven standalone kernel; gemm phases run as 256-thread teams
// (2 per block), idle halves mirror the team's 32 __syncthreads.
// ---------------------------------------------------------------------------
__global__ __launch_bounds__(512, 4) void fused_all(
    const float* x, const float* wq, const float* wout, const float* memory,
    const float* b_out,
    bf16* xb, bf16* wqb, bf16* mem_k, bf16* mem_vt, bf16* wob,
    bf16* q_ws, bf16* k_ws, bf16* vt_ws, float* out, int big, int nprep) {
  __shared__ __align__(16) char smem[65536];
  const int tid = threadIdx.x;
  const int half = tid >> 8;
  const int lt = tid & 255;
  char* ls = smem + half * 32768;
  cg::grid_group grid = cg::this_grid();

  // ---- Phase P: prep ----
  for (int vb = blockIdx.x * 2 + half; vb < nprep; vb += 1024)
    prep_vb(vb, lt, x, wq, memory, wout, xb, wqb, mem_k, mem_vt, wob);
  grid.sync();

  // ---- Phase G1: QKV gemm, 768 teams ----
  {
    int team = (half == 0) ? (int)blockIdx.x
                           : (blockIdx.x < 256 ? 512 + (int)blockIdx.x : -1);
    if (team >= 0) {
      gemm_team<0, false, 128>(team, lt, ls, ls + 16384, xb, wqb, nullptr,
                               q_ws, k_ws, vt_ws, nullptr, 1024, 24, 768);
    } else {
      for (int i = 0; i < 32; i++) __syncthreads();   // barrier mirror
    }
  }
  grid.sync();

  // ---- Phase A: attention ----
  attn_body(blockIdx.x, tid, smem, q_ws, k_ws, vt_ws, mem_k, mem_vt);
  grid.sync();

  // ---- Phase W: wout conv into wob (only when prep couldn't: wob aliased
  //      k_ws, which was live until attn finished) ----
  if (!big) {
    int gt = blockIdx.x * 512 + tid;
    if (gt < 131072) {
      size_t i = (size_t)gt * 8;
      f32x4 a = *(const f32x4*)(wout + i);
      f32x4 b = *(const f32x4*)(wout + i + 4);
      *(bf16x8*)(wob + i) = cvt8(a, b);
    }
    grid.sync();
  }

  // ---- Phase G2: out-projection, 512 teams ----
  {
    if (half == 0) {
      gemm_team<1, true, 64>((int)blockIdx.x, lt, ls, ls + 16384, q_ws, wob,
                             b_out, nullptr, nullptr, nullptr, out,
                             1024, 16, 512);
    } else {
      for (int i = 0; i < 32; i++) __syncthreads();   // barrier mirror
    }
  }
}

// ---------------------------------------------------------------------------
// Standalone fallback kernels (R9 structure) — used if cooperative launch
// is unavailable in this environment.
// ---------------------------------------------------------------------------
__global__ void prep_k(const float* __restrict__ x, const float* __restrict__ wq,
                       const float* __restrict__ memory,
                       const float* __restrict__ wout,
                       bf16* __restrict__ xb, bf16* __restrict__ wqb,
                       bf16* __restrict__ mem_k, bf16* __restrict__ mem_vt,
                       bf16* __restrict__ wob) {
  prep_vb(blockIdx.x, threadIdx.x, x, wq, memory, wout, xb, wqb,
          mem_k, mem_vt, wob);
}

__global__ void conv_bf16(const float* __restrict__ s, bf16* __restrict__ d) {
  size_t i = ((size_t)blockIdx.x * 256 + threadIdx.x) * 8;
  f32x4 a = *(const f32x4*)(s + i);
  f32x4 b = *(const f32x4*)(s + i + 4);
  *(bf16x8*)(d + i) = cvt8(a, b);
}

template <int EPI, bool APLANE, int NTILE>
__global__ __launch_bounds__(256, 3) void gemm_bt(
    const bf16* __restrict__ A, const bf16* __restrict__ W,
    const float* __restrict__ bias,
    bf16* __restrict__ q_ws, bf16* __restrict__ k_ws, bf16* __restrict__ vt_ws,
    float* __restrict__ Cout, int K) {
  __shared__ __align__(16) char ts[16384 + NTILE * 128];
  gemm_team<EPI, APLANE, NTILE>(
      blockIdx.y * gridDim.x + blockIdx.x, threadIdx.x, ts, ts + 16384,
      A, W, bias, q_ws, k_ws, vt_ws, Cout, K, gridDim.x,
      gridDim.x * gridDim.y);
}

__global__ __launch_bounds__(512, 4) void attn_kernel(
    bf16* __restrict__ q_ws, const bf16* __restrict__ k_ws,
    const bf16* __restrict__ vt_ws, const bf16* __restrict__ mem_k,
    const bf16* __restrict__ mem_vt) {
  __shared__ __align__(16) char smem[65536];
  attn_body(blockIdx.x, threadIdx.x, smem, q_ws, k_ws, vt_ws, mem_k, mem_vt);
}

// ---------------------------------------------------------------------------
// Scratch plan (unchanged):
//   ws:    q_ws 0-8M | k_ws 8-16M | vt_ws 16-24M | mem_k 24-25M | mem_vt 25-26M
//          | wob 26-28M (if ws_size >= 28M; else wob aliases k_ws, written
//          after attn by the fused Phase W / the conv fallback)
//   d_out: xb 0-8M | wqb 8-14M  [dead after gemm1; gemm2 overwrites d_out]
// ---------------------------------------------------------------------------
extern "C" void kernel_launch(void* const* d_in, const int* in_sizes, int n_in,
                              void* d_out, int out_size, void* d_ws,
                              size_t ws_size, hipStream_t stream) {
  const float* x      = (const float*)d_in[0];   // [B,T,D]   f32
  const float* w_qkv  = (const float*)d_in[1];   // [3D,D]    f32
  const float* w_out  = (const float*)d_in[2];   // [D,D]     f32
  const float* b_out  = (const float*)d_in[3];   // [D]       f32
  const float* memory = (const float*)d_in[4];   // [MEM,D]   f32

  char* ws = (char*)d_ws;
  bf16* q_ws   = (bf16*)(ws);                    // [32][2048][64]  8 MiB
  bf16* k_ws   = (bf16*)(ws + (8u << 20));       // [32][2048][64]  8 MiB
  bf16* vt_ws  = (bf16*)(ws + (16u << 20));      // [32][64][2048]  8 MiB
  bf16* mem_k  = (bf16*)(ws + (24u << 20));      // [16][512][64]   1 MiB
  bf16* mem_vt = (bf16*)(ws + (25u << 20));      // [1024][512]     1 MiB
  float* out = (float*)d_out;                    // f32 per reference

  char* outc = (char*)d_out;
  bf16* xb  = (bf16*)(outc);                     // 8 MiB scratch in d_out
  bf16* wqb = (bf16*)(outc + (8u << 20));        // 6 MiB scratch in d_out

  const bool big_ws = ws_size >= (28u << 20);
  bf16* wob = big_ws ? (bf16*)(ws + (26u << 20))   // private 2 MiB
                     : (bf16*)(ws + (8u << 20));   // aliases k_ws (post-attn)

  int bigi = big_ws ? 1 : 0;
  int nprep = big_ws ? 4608 : 4096;

  void* kargs[] = {
      (void*)&x, (void*)&w_qkv, (void*)&w_out, (void*)&memory, (void*)&b_out,
      (void*)&xb, (void*)&wqb, (void*)&mem_k, (void*)&mem_vt, (void*)&wob,
      (void*)&q_ws, (void*)&k_ws, (void*)&vt_ws, (void*)&out,
      (void*)&bigi, (void*)&nprep};

  hipError_t err = hipLaunchCooperativeKernel(
      (const void*)fused_all, dim3(512), dim3(512), kargs, 0, stream);

  if (err != hipSuccess) {
    (void)hipGetLastError();   // clear error state; use the 5-launch path
    prep_k<<<dim3(nprep), dim3(256), 0, stream>>>(
        x, w_qkv, memory, w_out, xb, wqb, mem_k, mem_vt, wob);
    gemm_bt<0, false, 128><<<dim3(24, 32), dim3(256), 0, stream>>>(
        xb, wqb, nullptr, q_ws, k_ws, vt_ws, nullptr, 1024);
    attn_kernel<<<dim3(512), dim3(512), 0, stream>>>(
        q_ws, k_ws, vt_ws, mem_k, mem_vt);
    if (!big_ws)
      conv_bf16<<<dim3(512), dim3(256), 0, stream>>>(w_out, wob);
    gemm_bt<1, true, 64><<<dim3(16, 32), dim3(256), 0, stream>>>(
        q_ws, wob, b_out, nullptr, nullptr, nullptr, out, 1024);
  }
}

// Round 13
// 180.460 us; speedup vs baseline: 2.1005x; 2.1005x over previous
//
#include <hip/hip_runtime.h>
#include <hip/hip_bf16.h>
#include <hip/hip_cooperative_groups.h>
#include <stdint.h>

namespace cg = cooperative_groups;

// Problem constants
#define B_   2
#define T_   2048
#define D_   1024
#define H_   16
#define HD_  64
#define MEM_ 512
#define KV_  (MEM_ + T_)   // 2560
#define NIT_ (KV_ / 64)    // 40 kv-tiles of 64
#define NIT2_ (NIT_ / 2)   // 20 per kv-half

using bf16 = __bf16;
typedef __bf16 bf16x8 __attribute__((ext_vector_type(8)));
typedef float  f32x4  __attribute__((ext_vector_type(4)));
typedef short  s16x4  __attribute__((ext_vector_type(4)));
typedef short  s16x8  __attribute__((ext_vector_type(8)));

__device__ __forceinline__ f32x4 mfma16(bf16x8 a, bf16x8 b, f32x4 c) {
  return __builtin_amdgcn_mfma_f32_16x16x32_bf16(a, b, c, 0, 0, 0);
}

// Async global->LDS, 16B per lane (dest = wave-uniform base + lane*16).
__device__ __forceinline__ void gll16(const void* g, void* l) {
  __builtin_amdgcn_global_load_lds(
      (const __attribute__((address_space(1))) unsigned int*)g,
      (__attribute__((address_space(3))) unsigned int*)l, 16, 0, 0);
}

__device__ __forceinline__ unsigned short bf16_bits(float f) {
  bf16 h = (bf16)f;
  return __builtin_bit_cast(unsigned short, h);
}

__device__ __forceinline__ ushort4 pack4(f32x4 v) {
  ushort4 p;
  p.x = bf16_bits(v[0]); p.y = bf16_bits(v[1]);
  p.z = bf16_bits(v[2]); p.w = bf16_bits(v[3]);
  return p;
}

__device__ __forceinline__ bf16x8 cvt8(f32x4 a, f32x4 b) {
  bf16x8 r;
  r[0] = (bf16)a[0]; r[1] = (bf16)a[1]; r[2] = (bf16)a[2]; r[3] = (bf16)a[3];
  r[4] = (bf16)b[0]; r[5] = (bf16)b[1]; r[6] = (bf16)b[2]; r[7] = (bf16)b[3];
  return r;
}

// V^T kv-column permutation within each 64-aligned tile (R9: conflicts -98.8%).
__device__ __forceinline__ int vperm4(int u) {   // u multiple of 4
  int g = u >> 4, c = (u >> 2) & 3;
  return (g >> 1) * 32 + c * 8 + (g & 1) * 4;
}

// ---------------------------------------------------------------------------
// prep body for one virtual 256-thread block `vb` (same dispatch as R9 prep).
// ---------------------------------------------------------------------------
__device__ __forceinline__ void prep_vb(
    int vb, int t, const float* __restrict__ x, const float* __restrict__ wq,
    const float* __restrict__ memory, const float* __restrict__ wout,
    bf16* __restrict__ xb, bf16* __restrict__ wqb,
    bf16* __restrict__ mem_k, bf16* __restrict__ mem_vt,
    bf16* __restrict__ wob) {
  if (vb < 3584) {
    const float* s = (vb < 2048) ? x : wq;
    bf16* d = (vb < 2048) ? xb : wqb;
    size_t i = ((size_t)(vb < 2048 ? vb : vb - 2048) * 256 + t) * 8;
    f32x4 a = *(const f32x4*)(s + i);
    f32x4 b = *(const f32x4*)(s + i + 4);
    *(bf16x8*)(d + i) = cvt8(a, b);
  } else if (vb < 3840) {
    int idx8 = ((vb - 3584) * 256 + t) * 8;   // [0, 512*1024)
    int m = idx8 >> 10, d0 = idx8 & 1023;
    int hh = d0 >> 6, hd0 = d0 & 63;
    f32x4 a = *(const f32x4*)(memory + idx8);
    f32x4 b = *(const f32x4*)(memory + idx8 + 4);
    *(bf16x8*)&mem_k[((size_t)hh * MEM_ + m) * HD_ + hd0] = cvt8(a, b);
  } else if (vb < 4096) {
    int idx = (vb - 3840) * 256 + t;          // [0, 65536)
    int d = idx & 1023;
    int m0 = (idx >> 10) * 8;                 // 0..511 step 8
    bf16x8 r;
#pragma unroll
    for (int j = 0; j < 8; j++)
      r[j] = (bf16)memory[(size_t)(m0 + j) * D_ + d];
    int u = m0 & 63;
    bf16* dst = &mem_vt[(size_t)d * MEM_ + (m0 - u) + vperm4(u)];
    s16x8 rb = __builtin_bit_cast(s16x8, r);
    *(s16x4*)dst = __builtin_shufflevector(rb, rb, 0, 1, 2, 3);
    *(s16x4*)(dst + 8) = __builtin_shufflevector(rb, rb, 4, 5, 6, 7);
  } else {
    size_t i = ((size_t)(vb - 4096) * 256 + t) * 8;
    f32x4 a = *(const f32x4*)(wout + i);
    f32x4 b = *(const f32x4*)(wout + i + 4);
    *(bf16x8*)(wob + i) = cvt8(a, b);
  }
}

// ---------------------------------------------------------------------------
// gemm team (256 threads): C[M,N] = A[M,K]*W[N,K]^T, 128 x NTILE tile, BK=64,
// 4 waves (2x2), gll16 staging, both-sides XOR chunk swizzle.  Exactly the
// R9 gemm_bt body, parameterized by team id / local tid / LDS slice.
// Contains exactly 2 * (K/64) __syncthreads() calls (mirror count: 32 @K=1024).
// ---------------------------------------------------------------------------
template <int EPI, bool APLANE, int NTILE>
__device__ __forceinline__ void gemm_team(
    int raw, int lt, char* AB, char* BB,
    const bf16* __restrict__ A, const bf16* __restrict__ W,
    const float* __restrict__ bias,
    bf16* __restrict__ q_ws, bf16* __restrict__ k_ws,
    bf16* __restrict__ vt_ws, float* __restrict__ Cout,
    int K, int gx, int nwg) {
  constexpr int NF = NTILE / 32;
  constexpr int NB = NTILE / 32;
  int lin = (raw & 7) * (nwg >> 3) + (raw >> 3);   // bijective XCD swizzle
  const int m0 = (lin / gx) * 128;
  const int n0 = (lin % gx) * NTILE;
  const int w = lt >> 6;
  const int lane = lt & 63;
  const int lx = lane & 15;
  const int quad = lane >> 4;
  const int amb = (w & 1) * 64;
  const int bnb = (w >> 1) * (NTILE / 2);
  const int srow = lt >> 3;
  const int cs = (lt & 7) ^ (srow & 7);

  f32x4 acc[4][NF];
#pragma unroll
  for (int i = 0; i < 4; i++)
#pragma unroll
    for (int j = 0; j < NF; j++) acc[i][j] = (f32x4){0.f, 0.f, 0.f, 0.f};

  for (int k0 = 0; k0 < K; k0 += 64) {
    const bf16* pa[4];
#pragma unroll
    for (int g = 0; g < 4; g++) {
      int r = srow + 32 * g;
      if constexpr (APLANE) {
        int hh = k0 >> 6, hd = cs * 8;
        int mA = m0 + r;
        pa[g] = A + ((size_t)((mA >> 11) * H_ + hh) * T_ + (mA & 2047)) * HD_ + hd;
      } else {
        pa[g] = A + (size_t)(m0 + r) * K + k0 + cs * 8;
      }
    }
    const bf16* pb[NB];
#pragma unroll
    for (int g = 0; g < NB; g++)
      pb[g] = W + (size_t)(n0 + srow + 32 * g) * K + k0 + cs * 8;

    __syncthreads();   // prev iteration's LDS reads done
#pragma unroll
    for (int g = 0; g < 4; g++) gll16(pa[g], AB + g * 4096 + lt * 16);
#pragma unroll
    for (int g = 0; g < NB; g++) gll16(pb[g], BB + g * 4096 + lt * 16);
    __syncthreads();   // drains vmcnt -> tiles valid

    bf16x8 bfr[NF][2];
    const int rk = (lx & 7) << 4;
#pragma unroll
    for (int nt = 0; nt < NF; nt++)
#pragma unroll
      for (int kh = 0; kh < 2; kh++)
        bfr[nt][kh] = *(const bf16x8*)(BB + (size_t)(bnb + nt * 16 + lx) * 128 +
                                       ((quad * 16 + kh * 64) ^ rk));
#pragma unroll
    for (int mt = 0; mt < 4; mt++) {
      const char* ar = AB + (size_t)(amb + mt * 16 + lx) * 128;
      bf16x8 af0 = *(const bf16x8*)(ar + ((quad * 16) ^ rk));
      bf16x8 af1 = *(const bf16x8*)(ar + ((quad * 16 + 64) ^ rk));
#pragma unroll
      for (int nt = 0; nt < NF; nt++) {
        acc[mt][nt] = mfma16(af0, bfr[nt][0], acc[mt][nt]);
        acc[mt][nt] = mfma16(af1, bfr[nt][1], acc[mt][nt]);
      }
    }
  }

  // Epilogue. C/D layout: row = quad*4+reg (m), col = lane&15 (n).
  if (EPI == 0) {
#pragma unroll
    for (int mt = 0; mt < 4; mt++) {
      int mbase = m0 + amb + mt * 16 + quad * 4;
      int b = mbase >> 11;        // T=2048
      int t = mbase & 2047;
#pragma unroll
      for (int nt = 0; nt < NF; nt++) {
        int col = n0 + bnb + nt * 16 + lx;     // [0,3072)
        int which = col >> 10;                 // 0=q 1=k 2=v
        int d = col & 1023;
        int hh = d >> 6, hdi = d & 63;
        int bh = b * H_ + hh;
        if (which == 0) {
#pragma unroll
          for (int r = 0; r < 4; r++)
            q_ws[((size_t)bh * T_ + t + r) * HD_ + hdi] = (bf16)acc[mt][nt][r];
        } else if (which == 1) {
#pragma unroll
          for (int r = 0; r < 4; r++)
            k_ws[((size_t)bh * T_ + t + r) * HD_ + hdi] = (bf16)acc[mt][nt][r];
        } else {
          int u = t & 63;
          *(ushort4*)&vt_ws[((size_t)bh * HD_ + hdi) * T_ + (t - u) +
                            vperm4(u)] = pack4(acc[mt][nt]);
        }
      }
    }
  } else {
#pragma unroll
    for (int nt = 0; nt < NF; nt++) {
      int col = n0 + bnb + nt * 16 + lx;
      float bias_f = bias[col];
#pragma unroll
      for (int mt = 0; mt < 4; mt++) {
        int mbase = m0 + amb + mt * 16 + quad * 4;
#pragma unroll
        for (int r = 0; r < 4; r++)
          Cout[(size_t)(mbase + r) * D_ + col] = acc[mt][nt][r] + bias_f;
      }
    }
  }
}

// ---------------------------------------------------------------------------
// Flash attention body (R9, proven 51 us): kv-split x2, 512 threads, b128 PV
// via vperm4, ones-MFMA row-sum, counted vmcnt, linear kv-half merge.
// smem: 64 KB (K 32KB | V 32KB).
// ---------------------------------------------------------------------------
__device__ __forceinline__ void attn_body(
    int bx, int tid, char* smem,
    bf16* __restrict__ q_ws, const bf16* __restrict__ k_ws,
    const bf16* __restrict__ vt_ws, const bf16* __restrict__ mem_k,
    const bf16* __restrict__ mem_vt) {
  char* KB = smem;
  char* VB = smem + 32768;
  const int wh = tid >> 8;             // kv-half
  const int t2 = tid & 255;
  const int w = t2 >> 6;               // wave within half
  const int lane = tid & 63;
  const int lx = lane & 15;
  const int quad = lane >> 4;
  const int bh = bx & 31;              // XCD-locality
  const int qt = bx >> 5;              // 16 q-tiles of 128
  const int q0 = qt * 128 + w * 32;
  const int h = bh & 15;

  const int srow1 = t2 >> 3;               // 0..31
  const int sc1 = (t2 & 7) ^ (srow1 & 7);  // pre-swizzled source chunk

  char* KBh = KB + wh * 16384;
  char* VBh = VB + wh * 16384;

  bf16* qbase = q_ws + ((size_t)bh * T_ + q0) * HD_;

  const bf16* kpl = k_ws + (size_t)bh * T_ * HD_;
  const bf16* vpl = vt_ws + (size_t)bh * HD_ * T_;
  const bf16* mkp = mem_k + (size_t)h * MEM_ * HD_;   // per-head plane
  const bf16* mvp = mem_vt + (size_t)h * HD_ * MEM_;

  auto stage = [&](int it2, int bi) {
    const int kv0 = (wh * NIT2_ + it2) * 64;
    const bf16 *kp1, *kp2, *vp1, *vp2;
    if (kv0 < MEM_) {
      kp1 = mkp + (size_t)(kv0 + srow1) * HD_ + sc1 * 8;
      kp2 = kp1 + (size_t)32 * HD_;
      vp1 = mvp + (size_t)srow1 * MEM_ + kv0 + sc1 * 8;
      vp2 = vp1 + (size_t)32 * MEM_;
    } else {
      const int t0 = kv0 - MEM_;
      kp1 = kpl + (size_t)(t0 + srow1) * HD_ + sc1 * 8;
      kp2 = kp1 + (size_t)32 * HD_;
      vp1 = vpl + (size_t)srow1 * T_ + t0 + sc1 * 8;
      vp2 = vp1 + (size_t)32 * T_;
    }
    char* kb = KBh + bi * 8192;
    char* vb = VBh + bi * 8192;
    gll16(kp1, kb + t2 * 16);
    gll16(kp2, kb + t2 * 16 + 4096);
    gll16(vp1, vb + t2 * 16);
    gll16(vp2, vb + t2 * 16 + 4096);
  };

  const float QSCALE = 0.125f * 1.44269504089f;
  bf16x8 qf[2][2];
#pragma unroll
  for (int qg = 0; qg < 2; qg++)
#pragma unroll
    for (int hf = 0; hf < 2; hf++) {
      bf16x8 v = *(const bf16x8*)(qbase + (size_t)(qg * 16 + lx) * HD_ +
                                  hf * 32 + quad * 8);
#pragma unroll
      for (int i = 0; i < 8; i++)
        v[i] = (bf16)((float)v[i] * QSCALE);
      qf[qg][hf] = v;
    }

  bf16x8 ones;
#pragma unroll
  for (int i = 0; i < 8; i++) ones[i] = (bf16)1.0f;

  f32x4 o[4][2];
#pragma unroll
  for (int mt = 0; mt < 4; mt++)
#pragma unroll
    for (int qg = 0; qg < 2; qg++) o[mt][qg] = (f32x4){0.f, 0.f, 0.f, 0.f};
  f32x4 osum[2] = {(f32x4){0.f, 0.f, 0.f, 0.f}, (f32x4){0.f, 0.f, 0.f, 0.f}};

  stage(0, 0);

  for (int it = 0; it < NIT2_; it++) {
    const int cur = it & 1;
    if (it + 1 < NIT2_) {
      stage(it + 1, cur ^ 1);
      asm volatile("s_waitcnt vmcnt(4)" ::: "memory");
    } else {
      asm volatile("s_waitcnt vmcnt(0)" ::: "memory");
    }
    __builtin_amdgcn_s_barrier();
    __builtin_amdgcn_sched_barrier(0);

    const char* KBc = KBh + cur * 8192;
    const char* VBc = VBh + cur * 8192;
    const int sw = (lx & 7) << 4;
    f32x4 s[4][2];
    __builtin_amdgcn_s_setprio(1);
#pragma unroll
    for (int g = 0; g < 4; g++) {
      const char* kb = KBc + (size_t)(g * 16 + lx) * 128;
      bf16x8 ka0 = *(const bf16x8*)(kb + ((quad * 16) ^ sw));
      bf16x8 ka1 = *(const bf16x8*)(kb + ((64 + quad * 16) ^ sw));
#pragma unroll
      for (int qg = 0; qg < 2; qg++) {
        s[g][qg] = (f32x4){0.f, 0.f, 0.f, 0.f};
        s[g][qg] = mfma16(ka0, qf[qg][0], s[g][qg]);
        s[g][qg] = mfma16(ka1, qf[qg][1], s[g][qg]);
      }
    }
    __builtin_amdgcn_s_setprio(0);

    s16x8 pk[2][2];
#pragma unroll
    for (int qg = 0; qg < 2; qg++) {
#pragma unroll
      for (int g = 0; g < 4; g++) {
#pragma unroll
        for (int r = 0; r < 4; r++) {
          float p = __builtin_amdgcn_exp2f(s[g][qg][r]);
          pk[qg][g >> 1][(g & 1) * 4 + r] = (short)bf16_bits(p);
        }
      }
    }

    __builtin_amdgcn_s_setprio(1);
#pragma unroll
    for (int mt = 0; mt < 4; mt++) {
      const char* vb = VBc + (size_t)(mt * 16 + lx) * 128;
#pragma unroll
      for (int p = 0; p < 2; p++) {
        bf16x8 va = *(const bf16x8*)(vb + ((p * 64 + quad * 16) ^ sw));
#pragma unroll
        for (int qg = 0; qg < 2; qg++)
          o[mt][qg] = mfma16(va, __builtin_bit_cast(bf16x8, pk[qg][p]),
                             o[mt][qg]);
      }
    }
#pragma unroll
    for (int p = 0; p < 2; p++)
#pragma unroll
      for (int qg = 0; qg < 2; qg++)
        osum[qg] = mfma16(ones, __builtin_bit_cast(bf16x8, pk[qg][p]),
                          osum[qg]);
    __builtin_amdgcn_s_setprio(0);

    __builtin_amdgcn_sched_barrier(0);
    __builtin_amdgcn_s_barrier();
  }

  float* OS = (float*)KB;
  float* OSS = (float*)VB;
  if (wh == 1) {
    float* dst = OS + t2 * 32;
#pragma unroll
    for (int mt = 0; mt < 4; mt++)
#pragma unroll
      for (int qg = 0; qg < 2; qg++) {
        int c = mt * 2 + qg;
        *(f32x4*)(dst + ((c ^ (t2 & 7)) * 4)) = o[mt][qg];
      }
    OSS[t2 * 2 + 0] = osum[0][0];
    OSS[t2 * 2 + 1] = osum[1][0];
  }
  __syncthreads();
  if (wh == 0) {
    const float* src = OS + t2 * 32;
    float inv[2] = {1.f / (osum[0][0] + OSS[t2 * 2 + 0]),
                    1.f / (osum[1][0] + OSS[t2 * 2 + 1])};
#pragma unroll
    for (int qg = 0; qg < 2; qg++) {
#pragma unroll
      for (int mt = 0; mt < 4; mt++) {
        int c = mt * 2 + qg;
        f32x4 po = *(const f32x4*)(src + ((c ^ (t2 & 7)) * 4));
        f32x4 ov;
#pragma unroll
        for (int r = 0; r < 4; r++) ov[r] = (o[mt][qg][r] + po[r]) * inv[qg];
        *(ushort4*)(qbase + (size_t)(qg * 16 + lx) * HD_ + mt * 16 + quad * 4)
            = pack4(ov);
      }
    }
  }
}

// ---------------------------------------------------------------------------
// FUSED cooperative kernel: prep -> gemm1 -> attn -> [wout conv] -> gemm2,
// grid 512 x 512 threads (2 blocks/CU), grid.sync() between phases.
// (512,2): VGPR cap 128 (gemm_team needs ~104, attn ~64 -> no spill, unlike
// R11's 64-cap).  LDS 64 KB -> 2 blocks/CU -> all 512 blocks co-resident.
// The host additionally verifies >=2 blocks/CU via the occupancy API before
// attempting the cooperative launch (guards the grid.sync deadlock window);
// any rejection falls back to the proven R9 5-launch path.
// ---------------------------------------------------------------------------
__global__ __launch_bounds__(512, 2) void fused_all(
    const float* x, const float* wq, const float* wout, const float* memory,
    const float* b_out,
    bf16* xb, bf16* wqb, bf16* mem_k, bf16* mem_vt, bf16* wob,
    bf16* q_ws, bf16* k_ws, bf16* vt_ws, float* out, int big, int nprep) {
  __shared__ __align__(16) char smem[65536];
  const int tid = threadIdx.x;
  const int half = tid >> 8;
  const int lt = tid & 255;
  char* ls = smem + half * 32768;
  cg::grid_group grid = cg::this_grid();

  // ---- Phase P: prep ----
  for (int vb = blockIdx.x * 2 + half; vb < nprep; vb += 1024)
    prep_vb(vb, lt, x, wq, memory, wout, xb, wqb, mem_k, mem_vt, wob);
  grid.sync();

  // ---- Phase G1: QKV gemm, 768 teams ----
  {
    int team = (half == 0) ? (int)blockIdx.x
                           : (blockIdx.x < 256 ? 512 + (int)blockIdx.x : -1);
    if (team >= 0) {
      gemm_team<0, false, 128>(team, lt, ls, ls + 16384, xb, wqb, nullptr,
                               q_ws, k_ws, vt_ws, nullptr, 1024, 24, 768);
    } else {
      for (int i = 0; i < 32; i++) __syncthreads();   // barrier mirror
    }
  }
  grid.sync();

  // ---- Phase A: attention ----
  attn_body(blockIdx.x, tid, smem, q_ws, k_ws, vt_ws, mem_k, mem_vt);
  grid.sync();

  // ---- Phase W: wout conv into wob (only when prep couldn't: wob aliased
  //      k_ws, which was live until attn finished) ----
  if (!big) {
    int gt = blockIdx.x * 512 + tid;
    if (gt < 131072) {
      size_t i = (size_t)gt * 8;
      f32x4 a = *(const f32x4*)(wout + i);
      f32x4 b = *(const f32x4*)(wout + i + 4);
      *(bf16x8*)(wob + i) = cvt8(a, b);
    }
    grid.sync();
  }

  // ---- Phase G2: out-projection, 512 teams ----
  {
    if (half == 0) {
      gemm_team<1, true, 64>((int)blockIdx.x, lt, ls, ls + 16384, q_ws, wob,
                             b_out, nullptr, nullptr, nullptr, out,
                             1024, 16, 512);
    } else {
      for (int i = 0; i < 32; i++) __syncthreads();   // barrier mirror
    }
  }
}

// ---------------------------------------------------------------------------
// Standalone fallback kernels (R9 structure, proven 180.8 us) — used if the
// cooperative launch is unavailable or cannot co-locate 2 blocks/CU.
// ---------------------------------------------------------------------------
__global__ void prep_k(const float* __restrict__ x, const float* __restrict__ wq,
                       const float* __restrict__ memory,
                       const float* __restrict__ wout,
                       bf16* __restrict__ xb, bf16* __restrict__ wqb,
                       bf16* __restrict__ mem_k, bf16* __restrict__ mem_vt,
                       bf16* __restrict__ wob) {
  prep_vb(blockIdx.x, threadIdx.x, x, wq, memory, wout, xb, wqb,
          mem_k, mem_vt, wob);
}

__global__ void conv_bf16(const float* __restrict__ s, bf16* __restrict__ d) {
  size_t i = ((size_t)blockIdx.x * 256 + threadIdx.x) * 8;
  f32x4 a = *(const f32x4*)(s + i);
  f32x4 b = *(const f32x4*)(s + i + 4);
  *(bf16x8*)(d + i) = cvt8(a, b);
}

template <int EPI, bool APLANE, int NTILE>
__global__ __launch_bounds__(256, 3) void gemm_bt(
    const bf16* __restrict__ A, const bf16* __restrict__ W,
    const float* __restrict__ bias,
    bf16* __restrict__ q_ws, bf16* __restrict__ k_ws, bf16* __restrict__ vt_ws,
    float* __restrict__ Cout, int K) {
  __shared__ __align__(16) char ts[16384 + NTILE * 128];
  gemm_team<EPI, APLANE, NTILE>(
      blockIdx.y * gridDim.x + blockIdx.x, threadIdx.x, ts, ts + 16384,
      A, W, bias, q_ws, k_ws, vt_ws, Cout, K, gridDim.x,
      gridDim.x * gridDim.y);
}

__global__ __launch_bounds__(512, 4) void attn_kernel(
    bf16* __restrict__ q_ws, const bf16* __restrict__ k_ws,
    const bf16* __restrict__ vt_ws, const bf16* __restrict__ mem_k,
    const bf16* __restrict__ mem_vt) {
  __shared__ __align__(16) char smem[65536];
  attn_body(blockIdx.x, threadIdx.x, smem, q_ws, k_ws, vt_ws, mem_k, mem_vt);
}

// ---------------------------------------------------------------------------
// Scratch plan (unchanged):
//   ws:    q_ws 0-8M | k_ws 8-16M | vt_ws 16-24M | mem_k 24-25M | mem_vt 25-26M
//          | wob 26-28M (if ws_size >= 28M; else wob aliases k_ws, written
//          after attn by the fused Phase W / the conv fallback)
//   d_out: xb 0-8M | wqb 8-14M  [dead after gemm1; gemm2 overwrites d_out]
// ---------------------------------------------------------------------------
extern "C" void kernel_launch(void* const* d_in, const int* in_sizes, int n_in,
                              void* d_out, int out_size, void* d_ws,
                              size_t ws_size, hipStream_t stream) {
  const float* x      = (const float*)d_in[0];   // [B,T,D]   f32
  const float* w_qkv  = (const float*)d_in[1];   // [3D,D]    f32
  const float* w_out  = (const float*)d_in[2];   // [D,D]     f32
  const float* b_out  = (const float*)d_in[3];   // [D]       f32
  const float* memory = (const float*)d_in[4];   // [MEM,D]   f32

  char* ws = (char*)d_ws;
  bf16* q_ws   = (bf16*)(ws);                    // [32][2048][64]  8 MiB
  bf16* k_ws   = (bf16*)(ws + (8u << 20));       // [32][2048][64]  8 MiB
  bf16* vt_ws  = (bf16*)(ws + (16u << 20));      // [32][64][2048]  8 MiB
  bf16* mem_k  = (bf16*)(ws + (24u << 20));      // [16][512][64]   1 MiB
  bf16* mem_vt = (bf16*)(ws + (25u << 20));      // [1024][512]     1 MiB
  float* out = (float*)d_out;                    // f32 per reference

  char* outc = (char*)d_out;
  bf16* xb  = (bf16*)(outc);                     // 8 MiB scratch in d_out
  bf16* wqb = (bf16*)(outc + (8u << 20));        // 6 MiB scratch in d_out

  const bool big_ws = ws_size >= (28u << 20);
  bf16* wob = big_ws ? (bf16*)(ws + (26u << 20))   // private 2 MiB
                     : (bf16*)(ws + (8u << 20));   // aliases k_ws (post-attn)

  int bigi = big_ws ? 1 : 0;
  int nprep = big_ws ? 4608 : 4096;

  // Safety gate: only take the cooperative path if the runtime confirms
  // >=2 resident blocks/CU for fused_all (512 blocks co-resident on 256 CUs).
  int maxb = 0;
  hipError_t qerr = hipOccupancyMaxActiveBlocksPerMultiprocessor(
      &maxb, (const void*)fused_all, 512, 0);
  bool try_coop = (qerr == hipSuccess) && (maxb >= 2);

  hipError_t err = hipErrorUnknown;
  if (try_coop) {
    void* kargs[] = {
        (void*)&x, (void*)&w_qkv, (void*)&w_out, (void*)&memory, (void*)&b_out,
        (void*)&xb, (void*)&wqb, (void*)&mem_k, (void*)&mem_vt, (void*)&wob,
        (void*)&q_ws, (void*)&k_ws, (void*)&vt_ws, (void*)&out,
        (void*)&bigi, (void*)&nprep};
    err = hipLaunchCooperativeKernel(
        (const void*)fused_all, dim3(512), dim3(512), kargs, 0, stream);
  }

  if (err != hipSuccess) {
    (void)hipGetLastError();   // clear error state; use the 5-launch path
    prep_k<<<dim3(nprep), dim3(256), 0, stream>>>(
        x, w_qkv, memory, w_out, xb, wqb, mem_k, mem_vt, wob);
    gemm_bt<0, false, 128><<<dim3(24, 32), dim3(256), 0, stream>>>(
        xb, wqb, nullptr, q_ws, k_ws, vt_ws, nullptr, 1024);
    attn_kernel<<<dim3(512), dim3(512), 0, stream>>>(
        q_ws, k_ws, vt_ws, mem_k, mem_vt);
    if (!big_ws)
      conv_bf16<<<dim3(512), dim3(256), 0, stream>>>(w_out, wob);
    gemm_bt<1, true, 64><<<dim3(16, 32), dim3(256), 0, stream>>>(
        q_ws, wob, b_out, nullptr, nullptr, nullptr, out, 1024);
  }
}